// Round 5
// baseline (391.557 us; speedup 1.0000x reference)
//
#include <hip/hip_runtime.h>
#include <stdint.h>

#define K_TOP 4096
#define CAP 8192            // candidate buffer (pow2, >= K_TOP + ties margin)

// ---- workspace layout (bytes) ----
static constexpr size_t HIST1_OFF = 0;                                   // 4096 u32 = 16 KB
static constexpr size_t HIST2_OFF = 16384;                               // 4096 u32 = 16 KB
static constexpr size_t SCAL_OFF  = 32768;                               // 64 B scalars
static constexpr size_t CAND_OFF  = 32832;                               // CAP u64 = 64 KB
static constexpr size_t TBOX_OFF  = CAND_OFF + (size_t)CAP * 8;          // K float4 = 64 KB
static constexpr size_t TSC_OFF   = TBOX_OFF + (size_t)K_TOP * 16;       // K float = 16 KB
static constexpr size_t MASK_OFF  = TSC_OFF + (size_t)K_TOP * 4;         // K*64 u64 = 2 MB
static constexpr size_t KEEP_OFF  = MASK_OFF + (size_t)K_TOP * 64 * 8;   // 64 u64
static constexpr size_t WS_NEED   = KEEP_OFF + 512;

// scal slots: [0]=B1 [1]=A1(count above B1) [4]=T24 threshold [5]=compact counter

typedef unsigned long long u64;

__device__ __forceinline__ unsigned ord_of(float s) {
    unsigned u = __float_as_uint(s);
    return (u & 0x80000000u) ? ~u : (u | 0x80000000u);
}

// P1: 12-bit histogram (bits 31..20 of ordered score), LDS-privatized, sparse atomic merge
__global__ void k_hist1(const float* __restrict__ scores, unsigned* __restrict__ hist, int n) {
    __shared__ unsigned h[4096];
    for (int j = threadIdx.x; j < 4096; j += 256) h[j] = 0;
    __syncthreads();
    int i = blockIdx.x * blockDim.x + threadIdx.x;
    int stride = gridDim.x * blockDim.x;
    for (; i < n; i += stride) {
        unsigned o = ord_of(scores[i]);
        atomicAdd(&h[o >> 20], 1u);
    }
    __syncthreads();
    for (int j = threadIdx.x; j < 4096; j += 256) {
        unsigned v = h[j];
        if (v) atomicAdd(&hist[j], v);
    }
}

// P2: 12-bit histogram of bits 19..8 among elements whose top-12 == B1
__global__ void k_hist2(const float* __restrict__ scores, const unsigned* __restrict__ scal,
                        unsigned* __restrict__ hist, int n) {
    __shared__ unsigned h[4096];
    for (int j = threadIdx.x; j < 4096; j += 256) h[j] = 0;
    __syncthreads();
    unsigned B1 = scal[0];
    int i = blockIdx.x * blockDim.x + threadIdx.x;
    int stride = gridDim.x * blockDim.x;
    for (; i < n; i += stride) {
        unsigned o = ord_of(scores[i]);
        if ((o >> 20) == B1) atomicAdd(&h[(o >> 8) & 4095u], 1u);
    }
    __syncthreads();
    for (int j = threadIdx.x; j < 4096; j += 256) {
        unsigned v = h[j];
        if (v) atomicAdd(&hist[j], v);
    }
}

// select threshold bin from a 4096-bin histogram via suffix scan
__global__ __launch_bounds__(1024) void k_select(const unsigned* __restrict__ hist,
                                                 unsigned* __restrict__ scal, int pass) {
    __shared__ unsigned buf[1024];
    int t = threadIdx.x;
    unsigned c0 = hist[t * 4 + 0], c1 = hist[t * 4 + 1];
    unsigned c2 = hist[t * 4 + 2], c3 = hist[t * 4 + 3];
    unsigned mysum = c0 + c1 + c2 + c3;
    buf[t] = mysum;
    __syncthreads();
    for (int off = 1; off < 1024; off <<= 1) {
        unsigned v = buf[t] + ((t + off < 1024) ? buf[t + off] : 0u);
        __syncthreads();
        buf[t] = v;
        __syncthreads();
    }
    unsigned target = (pass == 0) ? (unsigned)K_TOP : ((unsigned)K_TOP - scal[1]);
    unsigned sfx = buf[t];
    unsigned nxt = (t < 1023) ? buf[t + 1] : 0u;
    if (sfx >= target && nxt < target) {
        unsigned above = nxt;  // count in bins strictly above this 4-bin group
        unsigned b;
        if (above + c3 >= target)                { b = t * 4 + 3; }
        else if (above + c3 + c2 >= target)      { above += c3;           b = t * 4 + 2; }
        else if (above + c3 + c2 + c1 >= target) { above += c3 + c2;      b = t * 4 + 1; }
        else                                     { above += c3 + c2 + c1; b = t * 4 + 0; }
        if (pass == 0) { scal[0] = b; scal[1] = above; }
        else           { scal[4] = (scal[0] << 12) | b; }
    }
}

// compact all elements with 24-bit prefix >= T24, block-aggregated
__global__ __launch_bounds__(256) void k_compact(const float* __restrict__ scores,
                                                 const unsigned* __restrict__ scal,
                                                 u64* __restrict__ cand,
                                                 unsigned* __restrict__ counter, int n) {
    __shared__ unsigned lcount, lbase;
    __shared__ u64 lbuf[4096];
    if (threadIdx.x == 0) lcount = 0;
    __syncthreads();
    unsigned T = scal[4];
    int i = blockIdx.x * blockDim.x + threadIdx.x;
    int stride = gridDim.x * blockDim.x;
    for (; i < n; i += stride) {
        unsigned o = ord_of(scores[i]);
        if ((o >> 8) >= T) {
            unsigned p = atomicAdd(&lcount, 1u);
            lbuf[p] = ((u64)o << 32) | (unsigned)(~i);
        }
    }
    __syncthreads();
    if (threadIdx.x == 0) lbase = atomicAdd(counter, lcount);
    __syncthreads();
    for (unsigned j = threadIdx.x; j < lcount; j += 256) {
        unsigned p = lbase + j;
        if (p < CAP) cand[p] = lbuf[j];
    }
}

__device__ __forceinline__ float4 decode_clip(float4 a, float4 d) {
#pragma clang fp contract(off)
    const float BBOX_CLIP = (float)4.135166556742356;  // log(1000/16)
    float w  = a.z - a.x;
    float h  = a.w - a.y;
    float cx = a.x + 0.5f * w;
    float cy = a.y + 0.5f * h;
    float dx = d.x / 10.0f;
    float dy = d.y / 10.0f;
    float dw = fminf(d.z / 5.0f, BBOX_CLIP);
    float dh = fminf(d.w / 5.0f, BBOX_CLIP);
    float pcx = dx * w + cx;
    float pcy = dy * h + cy;
    float pw = (float)exp((double)dw) * w;
    float ph = (float)exp((double)dh) * h;
    float x1 = pcx - 0.5f * pw;
    float y1 = pcy - 0.5f * ph;
    float x2 = pcx + 0.5f * pw;
    float y2 = pcy + 0.5f * ph;
    x1 = fminf(fmaxf(x1, 0.0f), 1333.0f);
    y1 = fminf(fmaxf(y1, 0.0f), 800.0f);
    x2 = fminf(fmaxf(x2, 0.0f), 1333.0f);
    y2 = fminf(fmaxf(y2, 0.0f), 800.0f);
    return make_float4(x1, y1, x2, y2);
}

// rank-by-counting over candidates; decode straight into rank slot.
// keys are unique (index in low bits) -> ranks are a permutation of 0..M-1.
__global__ __launch_bounds__(256) void k_rank_gather(
        const float* __restrict__ scores, const float* __restrict__ anchors,
        const float* __restrict__ deltas, const u64* __restrict__ cand,
        const unsigned* __restrict__ scal, float4* __restrict__ tbox, float* __restrict__ tsc) {
    __shared__ u64 chunk[256];
    int t = threadIdx.x;
    int j = blockIdx.x * 256 + t;
    unsigned M = scal[5];
    if (M > CAP) M = CAP;
    u64 mykey = (j < (int)M) ? cand[j] : 0ULL;
    unsigned rank = 0;
    for (unsigned base = 0; base < M; base += 256) {
        unsigned idx = base + t;
        chunk[t] = (idx < M) ? cand[idx] : 0ULL;  // pad 0 < any valid key
        __syncthreads();
#pragma unroll 8
        for (int c = 0; c < 256; ++c) rank += (chunk[c] > mykey);
        __syncthreads();
    }
    if (j < (int)M && rank < K_TOP) {
        unsigned idx = ~(unsigned)mykey;
        float4 a = ((const float4*)anchors)[idx];
        float4 d = ((const float4*)deltas)[idx];
        tbox[rank] = decode_clip(a, d);
        tsc[rank]  = scores[idx];
    }
}

// suppression masks, upper-triangle blocks only. block = 64 threads (rows),
// grid = (colWord, rowBlock). Lower-triangle words are never written NOR read.
__global__ void k_mask(const float4* __restrict__ tbox, u64* __restrict__ mask) {
#pragma clang fp contract(off)
    int w = blockIdx.x;  // column word (64 cols)
    int r = blockIdx.y;  // row block
    int t = threadIdx.x;
    if (w < r) return;
    int i = r * 64 + t;
    __shared__ float4 cb[64];
    __shared__ float  ca[64];
    float4 b = tbox[w * 64 + t];
    cb[t] = b;
    ca[t] = (b.z - b.x) * (b.w - b.y);
    __syncthreads();
    float4 bi = tbox[i];
    float ai = (bi.z - bi.x) * (bi.w - bi.y);
    u64 bits = 0ULL;
    for (int c = 0; c < 64; ++c) {
        int j = w * 64 + c;
        if (j > i) {
            float4 bj = cb[c];
            float ltx = fmaxf(bi.x, bj.x);
            float lty = fmaxf(bi.y, bj.y);
            float rbx = fminf(bi.z, bj.z);
            float rby = fminf(bi.w, bj.w);
            float ww = fmaxf(rbx - ltx, 0.0f);
            float hh = fmaxf(rby - lty, 0.0f);
            float inter = ww * hh;
            float denom = ((ai + ca[c]) - inter) + 1e-9f;
            float iou = inter / denom;
            if (iou > 0.7f) bits |= (1ULL << c);
        }
    }
    mask[(size_t)i * 64 + w] = bits;
}

// 16-wave hierarchical greedy NMS, one block of 1024 threads.
// Raw s_barrier + lgkmcnt-only drain: global prefetch loads stay in flight
// across barriers (compiler inserts counted vmcnt at use). One barrier per
// block-step: every wave loads the diag tile and runs the 64-step chain
// redundantly. s_part parity-double-buffered to avoid cross-step races.
__global__ __launch_bounds__(1024, 1) void k_nms(const u64* __restrict__ mask,
                                                 u64* __restrict__ keep) {
    __shared__ u64 s_part[2][16];
    __shared__ u64 s_all[16][64];
    const int lane = threadIdx.x & 63;
    const int wv   = threadIdx.x >> 6;
    u64 myrem = 0ULL;

    u64 a0, a1, a2, a3, b0, b1, b2, b3, da, db;

    // issue row loads for block b (4 rows per wave), predicated to upper triangle
    #define ISSUE(b, r0, r1, r2, r3) do {                                      \
        int rr_ = (b) * 64 + wv * 4;                                           \
        bool p_ = (lane >= (b));                                               \
        r0 = p_ ? mask[((size_t)(rr_ + 0) << 6) + lane] : 0ULL;                \
        r1 = p_ ? mask[((size_t)(rr_ + 1) << 6) + lane] : 0ULL;                \
        r2 = p_ ? mask[((size_t)(rr_ + 2) << 6) + lane] : 0ULL;                \
        r3 = p_ ? mask[((size_t)(rr_ + 3) << 6) + lane] : 0ULL;                \
    } while (0)
    // every wave: lane c loads diag word b of row b*64+c (redundant across waves)
    #define DISSUE(b, d) do {                                                  \
        d = mask[((size_t)((b) * 64 + lane) << 6) + (b)];                      \
    } while (0)

    #define STEP(b, slot, r0, r1, r2, r3, d) do {                              \
        if (lane == (b)) s_part[slot][wv] = myrem;                             \
        asm volatile("s_waitcnt lgkmcnt(0)" ::: "memory");                     \
        __builtin_amdgcn_s_barrier();                                          \
        u64 rb_ = s_part[slot][0];                                             \
        _Pragma("unroll")                                                      \
        for (int k_ = 1; k_ < 16; ++k_) rb_ |= s_part[slot][k_];               \
        u64 w_ = ~rb_;                                                         \
        _Pragma("unroll")                                                      \
        for (int c_ = 0; c_ < 64; ++c_) {                                      \
            unsigned dlo_ = (unsigned)__builtin_amdgcn_readlane((int)(unsigned)(d), c_);   \
            unsigned dhi_ = (unsigned)__builtin_amdgcn_readlane((int)((d) >> 32), c_);     \
            u64 dc_ = ((u64)dhi_ << 32) | dlo_;                                \
            if ((w_ >> c_) & 1ULL) w_ &= ~dc_;                                 \
        }                                                                      \
        myrem |= ((u64)0 - ((w_ >> (wv * 4 + 0)) & 1ULL)) & r0;                \
        myrem |= ((u64)0 - ((w_ >> (wv * 4 + 1)) & 1ULL)) & r1;                \
        myrem |= ((u64)0 - ((w_ >> (wv * 4 + 2)) & 1ULL)) & r2;                \
        myrem |= ((u64)0 - ((w_ >> (wv * 4 + 3)) & 1ULL)) & r3;                \
    } while (0)

    ISSUE(0, a0, a1, a2, a3); DISSUE(0, da);
    ISSUE(1, b0, b1, b2, b3); DISSUE(1, db);
    for (int bb = 0; bb < 64; bb += 2) {
        STEP(bb, 0, a0, a1, a2, a3, da);
        if (bb + 2 < 64) { ISSUE(bb + 2, a0, a1, a2, a3); DISSUE(bb + 2, da); }
        STEP(bb + 1, 1, b0, b1, b2, b3, db);
        if (bb + 3 < 64) { ISSUE(bb + 3, b0, b1, b2, b3); DISSUE(bb + 3, db); }
    }
    #undef ISSUE
    #undef DISSUE
    #undef STEP

    s_all[wv][lane] = myrem;
    __syncthreads();
    if (wv == 0) {
        u64 tot = 0ULL;
#pragma unroll
        for (int k = 0; k < 16; ++k) tot |= s_all[k][lane];
        keep[lane] = ~tot;
    }
}

// write [K,5] output
__global__ void k_out(const float4* __restrict__ tbox, const float* __restrict__ tsc,
                      const u64* __restrict__ keep, float* __restrict__ out) {
    int j = blockIdx.x * blockDim.x + threadIdx.x;
    if (j >= K_TOP) return;
    bool kp = (keep[j >> 6] >> (j & 63)) & 1ULL;
    float4 b = tbox[j];
    float sc = tsc[j];
    float* o = out + (size_t)j * 5;
    o[0] = kp ? b.x : 0.0f;
    o[1] = kp ? b.y : 0.0f;
    o[2] = kp ? b.z : 0.0f;
    o[3] = kp ? b.w : 0.0f;
    o[4] = kp ? sc  : 0.0f;
}

extern "C" void kernel_launch(void* const* d_in, const int* in_sizes, int n_in,
                              void* d_out, int out_size, void* d_ws, size_t ws_size,
                              hipStream_t stream) {
    if (ws_size < WS_NEED) return;  // fail loudly (output stays poisoned)
    const float* scores  = (const float*)d_in[0];
    const float* anchors = (const float*)d_in[1];
    const float* deltas  = (const float*)d_in[2];
    int n = in_sizes[0];

    char* ws = (char*)d_ws;
    unsigned* hist1 = (unsigned*)(ws + HIST1_OFF);
    unsigned* hist2 = (unsigned*)(ws + HIST2_OFF);
    unsigned* scal  = (unsigned*)(ws + SCAL_OFF);
    u64* cand       = (u64*)(ws + CAND_OFF);
    float4* tbox    = (float4*)(ws + TBOX_OFF);
    float* tsc      = (float*)(ws + TSC_OFF);
    u64* mask       = (u64*)(ws + MASK_OFF);
    u64* keep       = (u64*)(ws + KEEP_OFF);

    hipMemsetAsync(ws, 0, SCAL_OFF + 64, stream);  // hist1 + hist2 + scalars

    k_hist1<<<256, 256, 0, stream>>>(scores, hist1, n);
    k_select<<<1, 1024, 0, stream>>>(hist1, scal, 0);
    k_hist2<<<256, 256, 0, stream>>>(scores, scal, hist2, n);
    k_select<<<1, 1024, 0, stream>>>(hist2, scal, 1);
    k_compact<<<256, 256, 0, stream>>>(scores, scal, cand, &scal[5], n);
    k_rank_gather<<<CAP / 256, 256, 0, stream>>>(scores, anchors, deltas, cand, scal, tbox, tsc);
    k_mask<<<dim3(64, 64), 64, 0, stream>>>(tbox, mask);
    k_nms<<<1, 1024, 0, stream>>>(mask, keep);
    k_out<<<16, 256, 0, stream>>>(tbox, tsc, keep, (float*)d_out);
}

// Round 6
// 259.811 us; speedup vs baseline: 1.5071x; 1.5071x over previous
//
#include <hip/hip_runtime.h>
#include <stdint.h>

#define K_TOP 4096
#define CAP 8192            // candidate buffer (pow2, >= K_TOP + ties margin)

// ---- workspace layout (bytes) ----
static constexpr size_t HIST1_OFF = 0;                                   // 4096 u32 = 16 KB
static constexpr size_t HIST2_OFF = 16384;                               // 4096 u32 = 16 KB
static constexpr size_t SCAL_OFF  = 32768;                               // 64 B scalars
static constexpr size_t ZPAD_OFF  = 32832;                               // 8 KB zeros (predication dummy)
static constexpr size_t CAND_OFF  = ZPAD_OFF + 8192 + 64;                // CAP u64 = 64 KB
static constexpr size_t TBOX_OFF  = CAND_OFF + (size_t)CAP * 8;          // K float4 = 64 KB
static constexpr size_t TSC_OFF   = TBOX_OFF + (size_t)K_TOP * 16;       // K float = 16 KB
static constexpr size_t MASK_OFF  = TSC_OFF + (size_t)K_TOP * 4;         // K*64 u64 = 2 MB
static constexpr size_t KEEP_OFF  = MASK_OFF + (size_t)K_TOP * 64 * 8;   // 64 u64
static constexpr size_t WS_NEED   = KEEP_OFF + 512;

// scal slots: [0]=B1 [1]=A1(count above B1) [4]=T24 threshold [5]=compact counter

typedef unsigned long long u64;

__device__ __forceinline__ unsigned ord_of(float s) {
    unsigned u = __float_as_uint(s);
    return (u & 0x80000000u) ? ~u : (u | 0x80000000u);
}

__device__ __forceinline__ u64 readlane64(u64 v, int l) {
    unsigned lo = (unsigned)__builtin_amdgcn_readlane((int)(unsigned)v, l);
    unsigned hi = (unsigned)__builtin_amdgcn_readlane((int)(v >> 32), l);
    return ((u64)hi << 32) | lo;
}

// P1: 12-bit histogram (bits 31..20 of ordered score), LDS-privatized, sparse atomic merge
__global__ void k_hist1(const float* __restrict__ scores, unsigned* __restrict__ hist, int n) {
    __shared__ unsigned h[4096];
    for (int j = threadIdx.x; j < 4096; j += 256) h[j] = 0;
    __syncthreads();
    int i = blockIdx.x * blockDim.x + threadIdx.x;
    int stride = gridDim.x * blockDim.x;
    for (; i < n; i += stride) {
        unsigned o = ord_of(scores[i]);
        atomicAdd(&h[o >> 20], 1u);
    }
    __syncthreads();
    for (int j = threadIdx.x; j < 4096; j += 256) {
        unsigned v = h[j];
        if (v) atomicAdd(&hist[j], v);
    }
}

// P2: 12-bit histogram of bits 19..8 among elements whose top-12 == B1
__global__ void k_hist2(const float* __restrict__ scores, const unsigned* __restrict__ scal,
                        unsigned* __restrict__ hist, int n) {
    __shared__ unsigned h[4096];
    for (int j = threadIdx.x; j < 4096; j += 256) h[j] = 0;
    __syncthreads();
    unsigned B1 = scal[0];
    int i = blockIdx.x * blockDim.x + threadIdx.x;
    int stride = gridDim.x * blockDim.x;
    for (; i < n; i += stride) {
        unsigned o = ord_of(scores[i]);
        if ((o >> 20) == B1) atomicAdd(&h[(o >> 8) & 4095u], 1u);
    }
    __syncthreads();
    for (int j = threadIdx.x; j < 4096; j += 256) {
        unsigned v = h[j];
        if (v) atomicAdd(&hist[j], v);
    }
}

// select threshold bin from a 4096-bin histogram via suffix scan
__global__ __launch_bounds__(1024) void k_select(const unsigned* __restrict__ hist,
                                                 unsigned* __restrict__ scal, int pass) {
    __shared__ unsigned buf[1024];
    int t = threadIdx.x;
    unsigned c0 = hist[t * 4 + 0], c1 = hist[t * 4 + 1];
    unsigned c2 = hist[t * 4 + 2], c3 = hist[t * 4 + 3];
    unsigned mysum = c0 + c1 + c2 + c3;
    buf[t] = mysum;
    __syncthreads();
    for (int off = 1; off < 1024; off <<= 1) {
        unsigned v = buf[t] + ((t + off < 1024) ? buf[t + off] : 0u);
        __syncthreads();
        buf[t] = v;
        __syncthreads();
    }
    unsigned target = (pass == 0) ? (unsigned)K_TOP : ((unsigned)K_TOP - scal[1]);
    unsigned sfx = buf[t];
    unsigned nxt = (t < 1023) ? buf[t + 1] : 0u;
    if (sfx >= target && nxt < target) {
        unsigned above = nxt;  // count in bins strictly above this 4-bin group
        unsigned b;
        if (above + c3 >= target)                { b = t * 4 + 3; }
        else if (above + c3 + c2 >= target)      { above += c3;           b = t * 4 + 2; }
        else if (above + c3 + c2 + c1 >= target) { above += c3 + c2;      b = t * 4 + 1; }
        else                                     { above += c3 + c2 + c1; b = t * 4 + 0; }
        if (pass == 0) { scal[0] = b; scal[1] = above; }
        else           { scal[4] = (scal[0] << 12) | b; }
    }
}

// compact all elements with 24-bit prefix >= T24, block-aggregated
__global__ __launch_bounds__(256) void k_compact(const float* __restrict__ scores,
                                                 const unsigned* __restrict__ scal,
                                                 u64* __restrict__ cand,
                                                 unsigned* __restrict__ counter, int n) {
    __shared__ unsigned lcount, lbase;
    __shared__ u64 lbuf[4096];
    if (threadIdx.x == 0) lcount = 0;
    __syncthreads();
    unsigned T = scal[4];
    int i = blockIdx.x * blockDim.x + threadIdx.x;
    int stride = gridDim.x * blockDim.x;
    for (; i < n; i += stride) {
        unsigned o = ord_of(scores[i]);
        if ((o >> 8) >= T) {
            unsigned p = atomicAdd(&lcount, 1u);
            lbuf[p] = ((u64)o << 32) | (unsigned)(~i);
        }
    }
    __syncthreads();
    if (threadIdx.x == 0) lbase = atomicAdd(counter, lcount);
    __syncthreads();
    for (unsigned j = threadIdx.x; j < lcount; j += 256) {
        unsigned p = lbase + j;
        if (p < CAP) cand[p] = lbuf[j];
    }
}

__device__ __forceinline__ float4 decode_clip(float4 a, float4 d) {
#pragma clang fp contract(off)
    const float BBOX_CLIP = (float)4.135166556742356;  // log(1000/16)
    float w  = a.z - a.x;
    float h  = a.w - a.y;
    float cx = a.x + 0.5f * w;
    float cy = a.y + 0.5f * h;
    float dx = d.x / 10.0f;
    float dy = d.y / 10.0f;
    float dw = fminf(d.z / 5.0f, BBOX_CLIP);
    float dh = fminf(d.w / 5.0f, BBOX_CLIP);
    float pcx = dx * w + cx;
    float pcy = dy * h + cy;
    float pw = (float)exp((double)dw) * w;
    float ph = (float)exp((double)dh) * h;
    float x1 = pcx - 0.5f * pw;
    float y1 = pcy - 0.5f * ph;
    float x2 = pcx + 0.5f * pw;
    float y2 = pcy + 0.5f * ph;
    x1 = fminf(fmaxf(x1, 0.0f), 1333.0f);
    y1 = fminf(fmaxf(y1, 0.0f), 800.0f);
    x2 = fminf(fmaxf(x2, 0.0f), 1333.0f);
    y2 = fminf(fmaxf(y2, 0.0f), 800.0f);
    return make_float4(x1, y1, x2, y2);
}

// rank-by-counting over candidates; decode straight into rank slot.
// keys are unique (index in low bits) -> ranks are a permutation of 0..M-1.
__global__ __launch_bounds__(256) void k_rank_gather(
        const float* __restrict__ scores, const float* __restrict__ anchors,
        const float* __restrict__ deltas, const u64* __restrict__ cand,
        const unsigned* __restrict__ scal, float4* __restrict__ tbox, float* __restrict__ tsc) {
    __shared__ u64 chunk[256];
    int t = threadIdx.x;
    int j = blockIdx.x * 256 + t;
    unsigned M = scal[5];
    if (M > CAP) M = CAP;
    u64 mykey = (j < (int)M) ? cand[j] : 0ULL;
    unsigned rank = 0;
    for (unsigned base = 0; base < M; base += 256) {
        unsigned idx = base + t;
        chunk[t] = (idx < M) ? cand[idx] : 0ULL;  // pad 0 < any valid key
        __syncthreads();
#pragma unroll 8
        for (int c = 0; c < 256; ++c) rank += (chunk[c] > mykey);
        __syncthreads();
    }
    if (j < (int)M && rank < K_TOP) {
        unsigned idx = ~(unsigned)mykey;
        float4 a = ((const float4*)anchors)[idx];
        float4 d = ((const float4*)deltas)[idx];
        tbox[rank] = decode_clip(a, d);
        tsc[rank]  = scores[idx];
    }
}

// suppression masks, upper-triangle blocks only. block = 64 threads (rows),
// grid = (colWord, rowBlock). Lower-triangle words are never written NOR read.
__global__ void k_mask(const float4* __restrict__ tbox, u64* __restrict__ mask) {
#pragma clang fp contract(off)
    int w = blockIdx.x;  // column word (64 cols)
    int r = blockIdx.y;  // row block
    int t = threadIdx.x;
    if (w < r) return;
    int i = r * 64 + t;
    __shared__ float4 cb[64];
    __shared__ float  ca[64];
    float4 b = tbox[w * 64 + t];
    cb[t] = b;
    ca[t] = (b.z - b.x) * (b.w - b.y);
    __syncthreads();
    float4 bi = tbox[i];
    float ai = (bi.z - bi.x) * (bi.w - bi.y);
    u64 bits = 0ULL;
    for (int c = 0; c < 64; ++c) {
        int j = w * 64 + c;
        if (j > i) {
            float4 bj = cb[c];
            float ltx = fmaxf(bi.x, bj.x);
            float lty = fmaxf(bi.y, bj.y);
            float rbx = fminf(bi.z, bj.z);
            float rby = fminf(bi.w, bj.w);
            float ww = fmaxf(rbx - ltx, 0.0f);
            float hh = fmaxf(rby - lty, 0.0f);
            float inter = ww * hh;
            float denom = ((ai + ca[c]) - inter) + 1e-9f;
            float iou = inter / denom;
            if (iou > 0.7f) bits |= (1ULL << c);
        }
    }
    mask[(size_t)i * 64 + w] = bits;
}

// Single-wave greedy NMS with an instruction-level load pipeline.
// lane l owns column word l. Per 64-row block: 64-step scalar chain on the
// prefetched diag tile, then apply 4x16 row-words from register buffers while
// issuing the next block's loads. asm-volatile loads + counted vmcnt keep
// 32..65 loads in flight at all times (no compiler sinking, no barrier drain).
// Lower-triangle words are predicated to a zeroed dummy buffer.
__global__ __launch_bounds__(64, 1) void k_nms(const u64* __restrict__ mask,
                                               const u64* __restrict__ zb,
                                               u64* __restrict__ keep) {
    const int lane = threadIdx.x;
    u64 remv = 0ULL;
    u64 c0[16], c1[16], c2[16], c3[16];
    u64 da, db;

#define GL0(dst, p)   asm volatile("global_load_dwordx2 %0, %1, off"             : "=&v"(dst) : "v"(p))
#define GL(dst, p, o) asm volatile("global_load_dwordx2 %0, %1, off offset:" #o  : "=&v"(dst) : "v"(p))

    // chunk ch (16 rows) of block blk: element (blk*64+ch*16+r)*64 + lane
    #define ISSUE_CHUNK(B, blk, ch) do {                                          \
        const u64* p_ = (lane >= (blk))                                           \
            ? (mask + (((size_t)(blk) << 12) + ((ch) << 10)) + lane) : zb;        \
        const u64* q_ = p_ + 512;                                                 \
        GL0(B[0], p_);      GL(B[1], p_, 512);  GL(B[2], p_, 1024);               \
        GL(B[3], p_, 1536); GL(B[4], p_, 2048); GL(B[5], p_, 2560);               \
        GL(B[6], p_, 3072); GL(B[7], p_, 3584);                                   \
        GL0(B[8], q_);      GL(B[9], q_, 512);  GL(B[10], q_, 1024);              \
        GL(B[11], q_, 1536); GL(B[12], q_, 2048); GL(B[13], q_, 2560);            \
        GL(B[14], q_, 3072); GL(B[15], q_, 3584);                                 \
    } while (0)

    // lane c holds diag word blk of row blk*64+c
    #define ISSUE_DIAG(D, blk) do {                                               \
        const u64* p_ = mask + ((((size_t)(blk) * 64 + lane)) << 6) + (blk);      \
        GL0(D, p_);                                                               \
    } while (0)

    #define WAITV(n) do {                                                         \
        asm volatile("s_waitcnt vmcnt(" #n ")" ::: "memory");                     \
        __builtin_amdgcn_sched_barrier(0);                                        \
    } while (0)

    #define CHAIN(b, D, w_)                                                       \
        u64 w_ = ~readlane64(remv, (b));                                          \
        do {                                                                      \
            _Pragma("unroll")                                                     \
            for (int ci_ = 0; ci_ < 64; ++ci_) {                                  \
                u64 dc_ = readlane64((D), ci_);                                   \
                if ((w_ >> ci_) & 1ULL) w_ &= ~dc_;                               \
            }                                                                     \
        } while (0)

    #define APPLY16(B, w_, k0) do {                                               \
        _Pragma("unroll")                                                         \
        for (int r_ = 0; r_ < 16; ++r_)                                           \
            remv |= ((u64)0 - ((w_ >> ((k0) + r_)) & 1ULL)) & B[r_];              \
    } while (0)

    // steady-state body: entry FIFO [C0,C1,diag_b,C2,C3]=65 outstanding
    #define BODY(b, Din, Dout) do {                                               \
        WAITV(32);                      /* retire C0,C1,diag_b */                 \
        CHAIN((b), Din, w_);                                                      \
        APPLY16(c0, w_, 0);  ISSUE_CHUNK(c0, (b) + 1, 0);                         \
        APPLY16(c1, w_, 16); ISSUE_CHUNK(c1, (b) + 1, 1); ISSUE_DIAG(Dout, (b)+1);\
        WAITV(49);                      /* retire C2 */                           \
        APPLY16(c2, w_, 32); ISSUE_CHUNK(c2, (b) + 1, 2);                         \
        WAITV(49);                      /* retire C3 */                           \
        APPLY16(c3, w_, 48); ISSUE_CHUNK(c3, (b) + 1, 3);                         \
    } while (0)

    // prologue: block 0 fully in flight
    ISSUE_DIAG(da, 0);
    ISSUE_CHUNK(c0, 0, 0); ISSUE_CHUNK(c1, 0, 1);
    ISSUE_CHUNK(c2, 0, 2); ISSUE_CHUNK(c3, 0, 3);

    for (int bb = 0; bb < 62; bb += 2) {
        BODY(bb, da, db);
        BODY(bb + 1, db, da);
    }
    BODY(62, da, db);

    // final block 63: no further issues
    WAITV(32);
    CHAIN(63, db, wl);
    APPLY16(c0, wl, 0); APPLY16(c1, wl, 16);
    WAITV(16);
    APPLY16(c2, wl, 32);
    WAITV(0);
    APPLY16(c3, wl, 48);

    keep[lane] = ~remv;

    #undef GL0
    #undef GL
    #undef ISSUE_CHUNK
    #undef ISSUE_DIAG
    #undef WAITV
    #undef CHAIN
    #undef APPLY16
    #undef BODY
}

// write [K,5] output
__global__ void k_out(const float4* __restrict__ tbox, const float* __restrict__ tsc,
                      const u64* __restrict__ keep, float* __restrict__ out) {
    int j = blockIdx.x * blockDim.x + threadIdx.x;
    if (j >= K_TOP) return;
    bool kp = (keep[j >> 6] >> (j & 63)) & 1ULL;
    float4 b = tbox[j];
    float sc = tsc[j];
    float* o = out + (size_t)j * 5;
    o[0] = kp ? b.x : 0.0f;
    o[1] = kp ? b.y : 0.0f;
    o[2] = kp ? b.z : 0.0f;
    o[3] = kp ? b.w : 0.0f;
    o[4] = kp ? sc  : 0.0f;
}

extern "C" void kernel_launch(void* const* d_in, const int* in_sizes, int n_in,
                              void* d_out, int out_size, void* d_ws, size_t ws_size,
                              hipStream_t stream) {
    if (ws_size < WS_NEED) return;  // fail loudly (output stays poisoned)
    const float* scores  = (const float*)d_in[0];
    const float* anchors = (const float*)d_in[1];
    const float* deltas  = (const float*)d_in[2];
    int n = in_sizes[0];

    char* ws = (char*)d_ws;
    unsigned* hist1 = (unsigned*)(ws + HIST1_OFF);
    unsigned* hist2 = (unsigned*)(ws + HIST2_OFF);
    unsigned* scal  = (unsigned*)(ws + SCAL_OFF);
    u64* zb         = (u64*)(ws + ZPAD_OFF);
    u64* cand       = (u64*)(ws + CAND_OFF);
    float4* tbox    = (float4*)(ws + TBOX_OFF);
    float* tsc      = (float*)(ws + TSC_OFF);
    u64* mask       = (u64*)(ws + MASK_OFF);
    u64* keep       = (u64*)(ws + KEEP_OFF);

    // zero hist1+hist2+scal+zpad in one shot
    hipMemsetAsync(ws, 0, ZPAD_OFF + 8192, stream);

    k_hist1<<<256, 256, 0, stream>>>(scores, hist1, n);
    k_select<<<1, 1024, 0, stream>>>(hist1, scal, 0);
    k_hist2<<<256, 256, 0, stream>>>(scores, scal, hist2, n);
    k_select<<<1, 1024, 0, stream>>>(hist2, scal, 1);
    k_compact<<<256, 256, 0, stream>>>(scores, scal, cand, &scal[5], n);
    k_rank_gather<<<CAP / 256, 256, 0, stream>>>(scores, anchors, deltas, cand, scal, tbox, tsc);
    k_mask<<<dim3(64, 64), 64, 0, stream>>>(tbox, mask);
    k_nms<<<1, 64, 0, stream>>>(mask, zb, keep);
    k_out<<<16, 256, 0, stream>>>(tbox, tsc, keep, (float*)d_out);
}